// Round 6
// baseline (33.846 us; speedup 1.0000x reference)
//
#include <hip/hip_runtime.h>

// Problem constants
#define NL 64
#define NR 4096
#define NE 32
#define NF 64
#define NP 8

// RBF math:  rbf = exp(-((d - mu_e)*3.2)^2) = exp2(-(d*DSCALE - e*MUSTEP)^2)
#define DSCALE 3.8435917081166390f   // 3.2 * sqrt(log2(e))
#define MUSTEP 1.2398683f            // (10/31) * DSCALE
#define EPS3   3e-10f                // eps added per coordinate (3 coords)

typedef _Float16 f16x8 __attribute__((ext_vector_type(8)));
typedef __fp16   h16x2 __attribute__((ext_vector_type(2)));   // cvt_pkrtz result
typedef float    f32x4 __attribute__((ext_vector_type(4)));

#define NBLK   2048                  // 256 r-blocks x 8 e-blocks
#define DS_TAB_BYTES (NL * NR * NP * 2)   // 4 MiB fp16 distance table in ws
// ws layout: [0, 4MiB) = ds16[l][r][p] ; [4MiB, +64KiB) = partials [8][NBLK]

// ---------------- distance table: ds16[l][r][p] = d(l,r,p)*DSCALE ------------
__global__ __launch_bounds__(256)
void ff_dist(const float* __restrict__ lig_coords,  // [8][64][3]
             const float* __restrict__ rec_coord,   // [4096][3]
             void* __restrict__ ws)
{
    const int tid = blockIdx.x * 256 + threadIdx.x;  // 262144 = 64*4096
    const int l = tid >> 12;          // uniform per block (4096 per l)
    const int r = tid & 4095;
    const float rx = rec_coord[r * 3 + 0];
    const float ry = rec_coord[r * 3 + 1];
    const float rz = rec_coord[r * 3 + 2];
    float d[NP];
#pragma unroll
    for (int p = 0; p < NP; ++p) {
        const float lx = lig_coords[(p * NL + l) * 3 + 0];  // scalar (l uniform)
        const float ly = lig_coords[(p * NL + l) * 3 + 1];
        const float lz = lig_coords[(p * NL + l) * 3 + 2];
        const float dx = lx - rx, dy = ly - ry, dz = lz - rz;
        const float d2 = fmaf(dx, dx, fmaf(dy, dy, fmaf(dz, dz, EPS3)));
        d[p] = __builtin_amdgcn_sqrtf(d2) * DSCALE;
    }
    union { h16x2 h[4]; uint4 u; } pk;
#pragma unroll
    for (int q = 0; q < 4; ++q)
        pk.h[q] = __builtin_amdgcn_cvt_pkrtz(d[2 * q], d[2 * q + 1]);
    ((uint4*)ws)[tid] = pk.u;
}

// ---------------- main: atn MFMA + RBF accumulate ---------------------------
// Grid: 2048 = rb(256) x eb(8). Block: 256 thr = 4 waves; wave wv owns the
// 16x16 tile (l = wv*16.., r = r0..), loops 4 e's. Only rec staged in LDS
// (shared by 4 waves); lig A-frags come straight from L2 (no intra-block reuse).
__global__ __launch_bounds__(256, 4)
void ff_main(const float* __restrict__ lig_feat,    // [64][32][64]
             const float* __restrict__ rec_feat,    // [4096][32][64]
             void* __restrict__ ws)
{
    __shared__ __align__(16) char recs[8192];  // [4e][16r][128B] swizzled fp16
    __shared__ float wred[32];

    const int t    = threadIdx.x;
    const int bid  = blockIdx.x;
    const int rb   = bid & 255;
    const int eb   = bid >> 8;
    const int r0   = rb * 16;
    const int e0   = eb * 4;
    const int lane = t & 63;
    const int wv   = t >> 6;
    const int l0   = wv * 16;
    const int cn   = lane & 15;       // MFMA col / B row (r offset)
    const int kg   = lane >> 4;       // k-group 0..3

    // ---- stage rec tile: per e, thread t handles (row=t>>4, f=(t&15)*4) ----
    const int srow = t >> 4, sf = (t & 15) * 4;
    const int swz = (8 * (t & 15)) ^ ((srow & 7) << 4);
#pragma unroll
    for (int e = 0; e < 4; ++e) {
        const float4 v = *(const float4*)&rec_feat[((r0 + srow) * NE + e0 + e) * NF + sf];
        union { h16x2 h[2]; uint2 u; } pk;
        pk.h[0] = __builtin_amdgcn_cvt_pkrtz(v.x, v.y);
        pk.h[1] = __builtin_amdgcn_cvt_pkrtz(v.z, v.w);
        *(uint2*)(recs + e * 2048 + srow * 128 + swz) = pk.u;
    }

    // ---- distances from precomputed table: (l = l0+kg*4+reg, r = r0+cn) ----
    const uint4* dtab = (const uint4*)ws;
    float ds[4][NP];
#pragma unroll
    for (int reg = 0; reg < 4; ++reg) {
        union { uint4 u; _Float16 h[8]; } pk;
        pk.u = dtab[(l0 + kg * 4 + reg) * NR + r0 + cn];
#pragma unroll
        for (int p = 0; p < NP; ++p) ds[reg][p] = (float)pk.h[p];
    }

    __syncthreads();   // rec tile ready

    // b-frag swizzled offsets (row = cn)
    const int bsw = (cn & 7) << 4;
    const int b_row = cn * 128;
    const int b0o = b_row + ((kg * 16) ^ bsw);
    const int b1o = b_row + ((kg * 16 + 64) ^ bsw);
    // lig A-frag global base: row l0+cn, k = kg*8 (+32)
    const float* ligb = &lig_feat[((l0 + cn) * NE + e0) * NF + kg * 8];

    float U[NP];
#pragma unroll
    for (int p = 0; p < NP; ++p) U[p] = 0.f;

#pragma unroll
    for (int ee = 0; ee < 4; ++ee) {
        const float4 af0 = *(const float4*)(ligb + ee * NF + 0);
        const float4 af1 = *(const float4*)(ligb + ee * NF + 4);
        const float4 af2 = *(const float4*)(ligb + ee * NF + 32);
        const float4 af3 = *(const float4*)(ligb + ee * NF + 36);
        union { h16x2 h[4]; f16x8 v; } a0, a1;
        a0.h[0] = __builtin_amdgcn_cvt_pkrtz(af0.x, af0.y);
        a0.h[1] = __builtin_amdgcn_cvt_pkrtz(af0.z, af0.w);
        a0.h[2] = __builtin_amdgcn_cvt_pkrtz(af1.x, af1.y);
        a0.h[3] = __builtin_amdgcn_cvt_pkrtz(af1.z, af1.w);
        a1.h[0] = __builtin_amdgcn_cvt_pkrtz(af2.x, af2.y);
        a1.h[1] = __builtin_amdgcn_cvt_pkrtz(af2.z, af2.w);
        a1.h[2] = __builtin_amdgcn_cvt_pkrtz(af3.x, af3.y);
        a1.h[3] = __builtin_amdgcn_cvt_pkrtz(af3.z, af3.w);
        const f16x8 b0 = *(const f16x8*)(recs + ee * 2048 + b0o);
        const f16x8 b1 = *(const f16x8*)(recs + ee * 2048 + b1o);
        f32x4 C = {0.f, 0.f, 0.f, 0.f};
        C = __builtin_amdgcn_mfma_f32_16x16x32_f16(a0.v, b0, C, 0, 0, 0);
        C = __builtin_amdgcn_mfma_f32_16x16x32_f16(a1.v, b1, C, 0, 0, 0);

        const float mu = (float)(e0 + ee) * MUSTEP;
#pragma unroll
        for (int reg = 0; reg < 4; ++reg) {
            const float a = C[reg];
#pragma unroll
            for (int p = 0; p < NP; ++p) {
                const float z = ds[reg][p] - mu;
                U[p] = fmaf(a, __builtin_amdgcn_exp2f(-(z * z)), U[p]);
            }
        }
    }

    // ---- reduce: wave shfl -> cross-wave via LDS -> per-block partial ------
#pragma unroll
    for (int p = 0; p < NP; ++p) {
        float v = U[p];
        for (int off = 32; off; off >>= 1) v += __shfl_down(v, off, 64);
        U[p] = v;
    }
    __syncthreads();                  // all rec reads done
    if (lane == 0) {
#pragma unroll
        for (int p = 0; p < NP; ++p) wred[wv * 8 + p] = U[p];
    }
    __syncthreads();
    float* wsP = (float*)((char*)ws + DS_TAB_BYTES);
    if (t < NP)
        wsP[t * NBLK + bid] = wred[t] + wred[8 + t] + wred[16 + t] + wred[24 + t];
}

__global__ __launch_bounds__(512)
void ff_fin(const void* __restrict__ ws,
            const float* __restrict__ w,
            const float* __restrict__ b,
            float* __restrict__ out) {
    const float* wsP = (const float*)((const char*)ws + DS_TAB_BYTES);
    const int t = threadIdx.x, lane = t & 63, p = t >> 6;
    float s = 0.f;
#pragma unroll
    for (int j = 0; j < NBLK / 256; ++j) {
        const float4 v = *(const float4*)&wsP[p * NBLK + j * 256 + lane * 4];
        s += (v.x + v.y) + (v.z + v.w);
    }
    for (int off = 32; off; off >>= 1) s += __shfl_down(s, off, 64);
    if (lane == 0) out[p] = fmaf(s, w[0], b[0]);
}

extern "C" void kernel_launch(void* const* d_in, const int* in_sizes, int n_in,
                              void* d_out, int out_size, void* d_ws, size_t ws_size,
                              hipStream_t stream) {
    const float* lig_feat   = (const float*)d_in[0];
    const float* rec_feat   = (const float*)d_in[1];
    const float* lig_coords = (const float*)d_in[2];
    const float* rec_coord  = (const float*)d_in[3];
    const float* weight     = (const float*)d_in[4];
    const float* bias       = (const float*)d_in[5];
    float* out = (float*)d_out;

    hipLaunchKernelGGL(ff_dist, dim3(1024), dim3(256), 0, stream,
                       lig_coords, rec_coord, d_ws);
    hipLaunchKernelGGL(ff_main, dim3(NBLK), dim3(256), 0, stream,
                       lig_feat, rec_feat, d_ws);
    hipLaunchKernelGGL(ff_fin, dim3(1), dim3(512), 0, stream,
                       d_ws, weight, bias, out);
}

// Round 7
// 29.408 us; speedup vs baseline: 1.1509x; 1.1509x over previous
//
#include <hip/hip_runtime.h>

// Problem constants
#define NL 64
#define NR 4096
#define NE 32
#define NF 64
#define NP 8

// RBF math:  rbf = exp(-((d - mu_e)*3.2)^2) = exp2(-(d*DSCALE - e*MUSTEP)^2)
#define DSCALE 3.8435917081166390f   // 3.2 * sqrt(log2(e))
#define MUSTEP 1.2398683f            // (10/31) * DSCALE
#define EPS3   3e-10f                // eps added per coordinate (3 coords)

typedef _Float16 f16x8 __attribute__((ext_vector_type(8)));
typedef __fp16   h16x2 __attribute__((ext_vector_type(2)));   // cvt_pkrtz result
typedef float    f32x4 __attribute__((ext_vector_type(4)));

#define NBLK 1024                     // 256 r-blocks x 4 e-blocks

// LDS map (40960 B total = exactly 4 blocks/CU at 160 KiB):
//   COORD [64 l][8 p][4 f32]          @ 0     : 8192 B (dead after build; wred alias)
//   DTAB  [64 l][16 r] uint4 fp16x8   @ 8192  : 16384 B, byte = l*256 + ((r*16)^((l&7)*16))
//   REC   [8 e][16 r][128 B swz]      @ 24576 : 16384 B, byte-in-row = (8*fq)^((r&7)*16)
#define COORD_B 0
#define DTAB_B  8192
#define REC_B   24576

__global__ __launch_bounds__(256, 4)
void ff_main(const float* __restrict__ lig_feat,    // [64][32][64]
             const float* __restrict__ rec_feat,    // [4096][32][64]
             const float* __restrict__ lig_coords,  // [8][64][3]
             const float* __restrict__ rec_coord,   // [4096][3]
             float* __restrict__ ws)                // [8][NBLK] partials
{
    __shared__ __align__(16) char smem[40960];

    const int t    = threadIdx.x;
    const int bid  = blockIdx.x;
    const int rb   = bid & 255;
    const int eb   = bid >> 8;
    const int r0   = rb * 16;
    const int e0   = eb * 8;
    const int lane = t & 63;
    const int wv   = t >> 6;
    const int l0   = wv * 16;
    const int cn   = lane & 15;       // MFMA col / frag row
    const int kg   = lane >> 4;       // k-group 0..3

    // ---- phase 1a: stage lig coords -> LDS [l][p][4] (coalesced src reads) ----
#pragma unroll
    for (int j = 0; j < 6; ++j) {
        const int s = j * 256 + t;            // 0..1535 over [8p][64l][3c]
        const int p = s / 192;
        const int rem = s - p * 192;
        const int l = rem / 3, c = rem - l * 3;
        *(float*)(smem + COORD_B + (l * 8 + p) * 16 + c * 4) = lig_coords[s];
    }
    // ---- phase 1b: stage rec feat tile -> LDS fp16 swizzled (independent) ----
    const int srow = t >> 4, sfq = t & 15;
    const int rswz = (8 * sfq) ^ ((srow & 7) << 4);
#pragma unroll
    for (int e = 0; e < 8; ++e) {
        const float4 v = *(const float4*)&rec_feat[((r0 + srow) * NE + e0 + e) * NF + sfq * 4];
        union { h16x2 h[2]; uint2 u; } pk;
        pk.h[0] = __builtin_amdgcn_cvt_pkrtz(v.x, v.y);
        pk.h[1] = __builtin_amdgcn_cvt_pkrtz(v.z, v.w);
        *(uint2*)(smem + REC_B + e * 2048 + srow * 128 + rswz) = pk.u;
    }
    __syncthreads();   // coords ready

    // ---- phase 2: build dist table [64 l][16 r] x 8p fp16 (thread: l=t>>2) ----
    {
        const int bl = t >> 2;
        const int br = t & 3;
        float4 lp[NP];
#pragma unroll
        for (int p = 0; p < NP; ++p)
            lp[p] = *(const float4*)(smem + COORD_B + (bl * 8 + p) * 16);
#pragma unroll
        for (int j = 0; j < 4; ++j) {
            const int r = br + 4 * j;
            const float rx = rec_coord[(r0 + r) * 3 + 0];
            const float ry = rec_coord[(r0 + r) * 3 + 1];
            const float rz = rec_coord[(r0 + r) * 3 + 2];
            float d[NP];
#pragma unroll
            for (int p = 0; p < NP; ++p) {
                const float dx = lp[p].x - rx, dy = lp[p].y - ry, dz = lp[p].z - rz;
                const float d2 = fmaf(dx, dx, fmaf(dy, dy, fmaf(dz, dz, EPS3)));
                d[p] = __builtin_amdgcn_sqrtf(d2) * DSCALE;
            }
            union { h16x2 h[4]; uint4 u; } pk;
#pragma unroll
            for (int q = 0; q < 4; ++q)
                pk.h[q] = __builtin_amdgcn_cvt_pkrtz(d[2 * q], d[2 * q + 1]);
            *(uint4*)(smem + DTAB_B + bl * 256 + ((r * 16) ^ ((bl & 7) * 16))) = pk.u;
        }
    }
    __syncthreads();   // dist table + rec tile ready

    // ---- phase 3: unpack this lane's 32 distances to fp32 regs ----
    float ds[4][NP];
#pragma unroll
    for (int reg = 0; reg < 4; ++reg) {
        const int l = l0 + kg * 4 + reg;
        union { uint4 u; _Float16 h[8]; } pk;
        pk.u = *(const uint4*)(smem + DTAB_B + l * 256 + ((cn * 16) ^ ((l & 7) * 16)));
#pragma unroll
        for (int p = 0; p < NP; ++p) ds[reg][p] = (float)pk.h[p];
    }

    // ---- phase 4: main loop over 8 e's ----
    const int bsw = (cn & 7) << 4;
    const int b0o = REC_B + cn * 128 + ((kg * 16) ^ bsw);
    const int b1o = REC_B + cn * 128 + ((kg * 16 + 64) ^ bsw);
    const float* ligb = &lig_feat[((l0 + cn) * NE + e0) * NF + kg * 8];

    float U[NP];
#pragma unroll
    for (int p = 0; p < NP; ++p) U[p] = 0.f;

#pragma unroll
    for (int ee = 0; ee < 8; ++ee) {
        const float4 af0 = *(const float4*)(ligb + ee * NF + 0);
        const float4 af1 = *(const float4*)(ligb + ee * NF + 4);
        const float4 af2 = *(const float4*)(ligb + ee * NF + 32);
        const float4 af3 = *(const float4*)(ligb + ee * NF + 36);
        union { h16x2 h[4]; f16x8 v; } a0, a1;
        a0.h[0] = __builtin_amdgcn_cvt_pkrtz(af0.x, af0.y);
        a0.h[1] = __builtin_amdgcn_cvt_pkrtz(af0.z, af0.w);
        a0.h[2] = __builtin_amdgcn_cvt_pkrtz(af1.x, af1.y);
        a0.h[3] = __builtin_amdgcn_cvt_pkrtz(af1.z, af1.w);
        a1.h[0] = __builtin_amdgcn_cvt_pkrtz(af2.x, af2.y);
        a1.h[1] = __builtin_amdgcn_cvt_pkrtz(af2.z, af2.w);
        a1.h[2] = __builtin_amdgcn_cvt_pkrtz(af3.x, af3.y);
        a1.h[3] = __builtin_amdgcn_cvt_pkrtz(af3.z, af3.w);
        const f16x8 b0 = *(const f16x8*)(smem + b0o + ee * 2048);
        const f16x8 b1 = *(const f16x8*)(smem + b1o + ee * 2048);
        f32x4 C = {0.f, 0.f, 0.f, 0.f};
        C = __builtin_amdgcn_mfma_f32_16x16x32_f16(a0.v, b0, C, 0, 0, 0);
        C = __builtin_amdgcn_mfma_f32_16x16x32_f16(a1.v, b1, C, 0, 0, 0);

        const float mu = (float)(e0 + ee) * MUSTEP;
#pragma unroll
        for (int reg = 0; reg < 4; ++reg) {
            const float a = C[reg];
#pragma unroll
            for (int p = 0; p < NP; ++p) {
                const float z = ds[reg][p] - mu;
                U[p] = fmaf(a, __builtin_amdgcn_exp2f(-(z * z)), U[p]);
            }
        }
    }

    // ---- phase 5: reduce (wave shfl -> cross-wave via COORD alias) ----
#pragma unroll
    for (int p = 0; p < NP; ++p) {
        float v = U[p];
        for (int off = 32; off; off >>= 1) v += __shfl_down(v, off, 64);
        U[p] = v;
    }
    float* wred = (float*)(smem + COORD_B);   // COORD dead since phase 2
    if (lane == 0) {
#pragma unroll
        for (int p = 0; p < NP; ++p) wred[wv * 8 + p] = U[p];
    }
    __syncthreads();
    if (t < NP)
        ws[t * NBLK + bid] = wred[t] + wred[8 + t] + wred[16 + t] + wred[24 + t];
}

__global__ __launch_bounds__(512)
void ff_fin(const float* __restrict__ ws,
            const float* __restrict__ w,
            const float* __restrict__ b,
            float* __restrict__ out) {
    const int t = threadIdx.x, lane = t & 63, p = t >> 6;
    float s = 0.f;
#pragma unroll
    for (int j = 0; j < NBLK / 256; ++j) {
        const float4 v = *(const float4*)&ws[p * NBLK + j * 256 + lane * 4];
        s += (v.x + v.y) + (v.z + v.w);
    }
    for (int off = 32; off; off >>= 1) s += __shfl_down(s, off, 64);
    if (lane == 0) out[p] = fmaf(s, w[0], b[0]);
}

extern "C" void kernel_launch(void* const* d_in, const int* in_sizes, int n_in,
                              void* d_out, int out_size, void* d_ws, size_t ws_size,
                              hipStream_t stream) {
    const float* lig_feat   = (const float*)d_in[0];
    const float* rec_feat   = (const float*)d_in[1];
    const float* lig_coords = (const float*)d_in[2];
    const float* rec_coord  = (const float*)d_in[3];
    const float* weight     = (const float*)d_in[4];
    const float* bias       = (const float*)d_in[5];
    float* out = (float*)d_out;
    float* ws  = (float*)d_ws;

    hipLaunchKernelGGL(ff_main, dim3(NBLK), dim3(256), 0, stream,
                       lig_feat, rec_feat, lig_coords, rec_coord, ws);
    hipLaunchKernelGGL(ff_fin, dim3(1), dim3(512), 0, stream,
                       ws, weight, bias, out);
}